// Round 12
// baseline (607.172 us; speedup 1.0000x reference)
//
#include <hip/hip_runtime.h>
#include <cstdint>
#include <cstddef>

// ---------------------------------------------------------------------------
// SelfModifyingRecurrent: B=8192, E=1024, L=3
//   * h_prev stays ZERO -> gh = b_hh (const), no W_hh GEMM
//   * weight modification is rank-1 -> gi += cond * 0.01*dot(cur, mean_sig)
// R10 fix: R9's counted-vmcnt pipeline raced — raw s_barrier without lgkm
// drain let STAGE overwrite a buffer whose ds_reads were still in flight
// (rule #18: compiler sinks MFMAs + lgkm waits past inline-asm barriers).
// Fix (m201 discipline): vwait -> s_waitcnt lgkmcnt(0) -> sched_barrier(0)
// -> s_barrier -> sched_barrier(0) -> STAGE -> compute. Everything else
// identical to R9: BK=32, 4 LDS buffers, 3 stages in flight, counted vmcnt
// (drain only in the 2 tail steps), fused GRU epilogue, 2 blocks/CU.
// ---------------------------------------------------------------------------

#define BSZ 8192
#define ESZ 1024

typedef _Float16 f16x8 __attribute__((ext_vector_type(8)));
typedef float    f32x4 __attribute__((ext_vector_type(4)));
typedef unsigned short u16;
typedef u16 u16x4 __attribute__((ext_vector_type(4)));

__device__ __forceinline__ u16 f2h(float f) {
    _Float16 h = (_Float16)f;
    return __builtin_bit_cast(u16, h);
}
__device__ __forceinline__ float h2f(u16 h) {
    return (float)__builtin_bit_cast(_Float16, h);
}

__device__ __forceinline__ void gload16(const void* g, void* l) {
    __builtin_amdgcn_global_load_lds((const __attribute__((address_space(1))) void*)g,
                                     (__attribute__((address_space(3))) void*)l,
                                     16, 0, 0);
}

template <int N>
__device__ __forceinline__ void vwait() {
    if constexpr (N == 0)       asm volatile("s_waitcnt vmcnt(0)" ::: "memory");
    else if constexpr (N == 3)  asm volatile("s_waitcnt vmcnt(3)" ::: "memory");
    else if constexpr (N == 4)  asm volatile("s_waitcnt vmcnt(4)" ::: "memory");
    else if constexpr (N == 5)  asm volatile("s_waitcnt vmcnt(5)" ::: "memory");
    else if constexpr (N == 6)  asm volatile("s_waitcnt vmcnt(6)" ::: "memory");
    else if constexpr (N == 8)  asm volatile("s_waitcnt vmcnt(8)" ::: "memory");
    else if constexpr (N == 10) asm volatile("s_waitcnt vmcnt(10)" ::: "memory");
}

__device__ __forceinline__ float sigmoidf_(float x) {
    return 1.f / (1.f + __expf(-x));
}
__device__ __forceinline__ float tanhf_(float x) {
    float cx = fminf(fmaxf(x, -15.f), 15.f);
    float e = __expf(2.f * cx);
    return (e - 1.f) / (e + 1.f);
}

// ---------------------------------------------------------------------------
// fused fp32 -> f16 conversion for Wih, W1, W2, x (one launch)
// ---------------------------------------------------------------------------
#define N4_WIH (3 * 3072 * 1024 / 4)
#define N4_W1  (3 * 512 * 1024 / 4)
#define N4_W2  (3 * 1024 * 512 / 4)
#define N4_X   (BSZ * ESZ / 4)

__global__ void cvt_all_kernel(const float* __restrict__ Wih, const float* __restrict__ W1,
                               const float* __restrict__ W2, const float* __restrict__ x,
                               u16* __restrict__ oWih, u16* __restrict__ oW1,
                               u16* __restrict__ oW2, u16* __restrict__ ox) {
    int i = blockIdx.x * 256 + threadIdx.x;
    const float* in;
    u16* out;
    if (i < N4_WIH) { in = Wih; out = oWih; }
    else if (i < N4_WIH + N4_W1) { i -= N4_WIH; in = W1; out = oW1; }
    else if (i < N4_WIH + N4_W1 + N4_W2) { i -= N4_WIH + N4_W1; in = W2; out = oW2; }
    else { i -= N4_WIH + N4_W1 + N4_W2; if (i >= N4_X) return; in = x; out = ox; }
    f32x4 v = ((const f32x4*)in)[i];
    u16x4 o;
    o.x = f2h(v.x); o.y = f2h(v.y); o.z = f2h(v.z); o.w = f2h(v.w);
    ((u16x4*)out)[i] = o;
}

// ---------------------------------------------------------------------------
// Gate kernel (reads f16 cur): per row r:
//   gate_r = sigmoid(dot(cur_r, Wg) + bg)       -> atomic sum into gsum
//   sdot_r = dot(cur_r, colsum_sig)*(0.01/B)
// ---------------------------------------------------------------------------
__global__ void gate_kernel(const u16* __restrict__ cur, const float* __restrict__ Wg,
                            const float* __restrict__ bg, const float* __restrict__ colsum,
                            float* __restrict__ gsum, float* __restrict__ sdot) {
    const int wid = threadIdx.x >> 6, lane = threadIdx.x & 63;
    const int row = blockIdx.x * 4 + wid;
    const u16* cr = cur + (size_t)row * ESZ;
    float pg = 0.f, pm = 0.f;
#pragma unroll
    for (int h = 0; h < 2; h++) {
        int base = lane * 16 + h * 8;
        f16x8 cv = *(const f16x8*)(cr + base);
#pragma unroll
        for (int q = 0; q < 2; q++) {
            f32x4 wv = *(const f32x4*)(Wg + base + q * 4);
            f32x4 mv = *(const f32x4*)(colsum + base + q * 4);
#pragma unroll
            for (int e = 0; e < 4; e++) {
                float c = (float)cv[q * 4 + e];
                pg += c * wv[e];
                pm += c * mv[e];
            }
        }
    }
#pragma unroll
    for (int s = 32; s >= 1; s >>= 1) {
        pg += __shfl_xor(pg, s);
        pm += __shfl_xor(pm, s);
    }
    __shared__ float gp[4];
    if (lane == 0) {
        gp[wid] = sigmoidf_(pg + bg[0]);
        sdot[row] = pm * (0.01f / 8192.f);
    }
    __syncthreads();
    if (threadIdx.x == 0) atomicAdd(gsum, gp[0] + gp[1] + gp[2] + gp[3]);
}

// ---------------------------------------------------------------------------
// Pipelined GEMM template (T4 counted vmcnt, race-fixed).
// BM = BMF*32 rows x (NG x 64 cols), BK=32, 4 waves (2M x 2N), 256 thr.
// 4 LDS buffers; 3 stages in flight; per step:
//   vwait(2*LPS) -> lgkmcnt(0) -> SB(0) -> s_barrier -> SB(0)
//   -> STAGE(kt+3) -> ds_read+MFMA(kt)
// (tail: vwait(LPS) at NK-2, vwait(0) at NK-1). LPS = BMF/2 + NG loads/thread.
// lgkmcnt(0)-before-barrier closes the R9 race: no wave can signal the
// barrier while its LDS reads of the buffer about to be overwritten are
// still in flight. Swizzle both-sides: slot = (chunk ^ row ^ (row>>2)) & 3.
// Grid: 8 XCDs x PPX row-panels x col-chunks (A panel chunk L2-resident).
// EPI 0: relu->f16; EPI 1: tanh->f16 + colsum atomics; EPI 2: GRU cell.
// ---------------------------------------------------------------------------
template <int BMF, int NG, int NK, int LPS, int PPX, int CW, int K, int EPI>
__global__ void __launch_bounds__(256, 2) gemm_p4_kernel(
    const u16* __restrict__ A, const u16* __restrict__ W,
    const float* __restrict__ bias, const float* __restrict__ bhh,
    const u16* __restrict__ sig, const float* __restrict__ sdot,
    const float* __restrict__ gsum, u16* __restrict__ outp,
    float* __restrict__ curf_out, float* __restrict__ colsum, int N) {
    constexpr int BM = BMF * 32;
    __shared__ u16 lA[4][BM * 32];
    __shared__ u16 lB[4][NG * 64 * 32];
    const int t = threadIdx.x;
    const int xcd = blockIdx.x & 7, q = blockIdx.x >> 3;
    const int m0 = (xcd * PPX + (q % PPX)) * BM;
    const int c0 = (q / PPX) * CW;
    const int wid = t >> 6, lane = t & 63;
    const int waver = wid >> 1, wavec = wid & 1;
    const int lrow = lane & 15, lk = lane >> 4;

    f32x4 acc[BMF][2 * NG] = {};

    auto STAGE = [&](int buf, int k0) {
#pragma unroll
        for (int i = 0; i < BMF / 2; i++) {
            int ci = i * 256 + t;                    // 16B chunk index
            int r = ci >> 2;
            int slot = (ci ^ r ^ (r >> 2)) & 3;      // pre-swizzled source col
            gload16(A + (size_t)(m0 + r) * K + k0 + slot * 8, &lA[buf][ci * 8]);
        }
#pragma unroll
        for (int i = 0; i < NG; i++) {
            int ci = i * 256 + t;
            int r = ci >> 2;
            int g = r >> 6, rl = r & 63;
            int wrow = (EPI == 2) ? (g * 1024 + c0 + rl) : (c0 + g * 64 + rl);
            int slot = (ci ^ r ^ (r >> 2)) & 3;
            gload16(W + (size_t)wrow * K + k0 + slot * 8, &lB[buf][ci * 8]);
        }
    };

    STAGE(0, 0);
    STAGE(1, 32);
    STAGE(2, 64);
    for (int kt = 0; kt < NK; ++kt) {
        if (kt <= NK - 3) vwait<2 * LPS>();          // stage kt done; kt+1,kt+2 in flight
        else if (kt == NK - 2) vwait<LPS>();
        else vwait<0>();
        // Drain this wave's LDS reads (of buffer kt-1, about to be overwritten
        // by STAGE(kt+3) below) BEFORE signalling the barrier. Closes R9 race.
        asm volatile("s_waitcnt lgkmcnt(0)" ::: "memory");
        __builtin_amdgcn_sched_barrier(0);
        __builtin_amdgcn_s_barrier();
        __builtin_amdgcn_sched_barrier(0);
        if (kt + 4 <= NK) STAGE((kt + 3) & 3, (kt + 3) * 32);
        const int cb = kt & 3;
        f16x8 af[BMF];
#pragma unroll
        for (int m = 0; m < BMF; m++) {
            int ar = waver * (BMF * 16) + m * 16 + lrow;
            af[m] = *(const f16x8*)&lA[cb][ar * 32 + ((lk ^ ar ^ (ar >> 2)) & 3) * 8];
        }
#pragma unroll
        for (int g = 0; g < NG; g++) {
#pragma unroll
            for (int n = 0; n < 2; n++) {
                int br = g * 64 + wavec * 32 + n * 16 + lrow;
                f16x8 bf = *(const f16x8*)&lB[cb][br * 32 + ((lk ^ br ^ (br >> 2)) & 3) * 8];
#pragma unroll
                for (int m = 0; m < BMF; m++)
                    acc[m][g * 2 + n] =
                        __builtin_amdgcn_mfma_f32_16x16x32_f16(af[m], bf, acc[m][g * 2 + n], 0, 0, 0);
            }
        }
    }

    if constexpr (EPI == 2) {
        const bool cond = (*gsum) > 4096.f;          // mean(gate) > 0.5
#pragma unroll
        for (int m = 0; m < BMF; m++) {
            int rbase = m0 + waver * (BMF * 16) + m * 16 + lk * 4;
            float corr[4];
#pragma unroll
            for (int j = 0; j < 4; j++) corr[j] = cond ? sdot[rbase + j] : 0.f;
#pragma unroll
            for (int n = 0; n < 2; n++) {
                int c = c0 + wavec * 32 + n * 16 + lrow;
                float br = bias[c], bz = bias[1024 + c], bn = bias[2048 + c];
                float hr = bhh[c], hz = bhh[1024 + c], hn = bhh[2048 + c];
#pragma unroll
                for (int j = 0; j < 4; j++) {
                    float ir = acc[m][0 + n][j] + br + corr[j];
                    float iz = acc[m][2 + n][j] + bz + corr[j];
                    float inn = acc[m][4 + n][j] + bn + corr[j];
                    float r = sigmoidf_(ir + hr);
                    float z = sigmoidf_(iz + hz);
                    float nn = tanhf_(inn + r * hn);
                    float o = (1.f - z) * nn + h2f(sig[(size_t)(rbase + j) * 1024 + c]);
                    if (curf_out) curf_out[(size_t)(rbase + j) * 1024 + c] = o;
                    if (outp) outp[(size_t)(rbase + j) * 1024 + c] = f2h(o);
                }
            }
        }
    } else {
#pragma unroll
        for (int g = 0; g < NG; g++) {
#pragma unroll
            for (int n = 0; n < 2; n++) {
                int c = c0 + g * 64 + wavec * 32 + n * 16 + lrow;
                float bv = bias[c];
                float cs = 0.f;
#pragma unroll
                for (int m = 0; m < BMF; m++) {
                    int rbase = m0 + waver * (BMF * 16) + m * 16 + lk * 4;
#pragma unroll
                    for (int j = 0; j < 4; j++) {
                        float v = acc[m][g * 2 + n][j] + bv;
                        if (EPI == 0) {
                            v = v > 0.f ? v : 0.f;
                            outp[(size_t)(rbase + j) * N + c] = f2h(v);
                        } else {
                            float tv = tanhf_(v);
                            outp[(size_t)(rbase + j) * N + c] = f2h(tv);
                            cs += tv;
                        }
                    }
                }
                if (EPI == 1) {
                    cs += __shfl_xor(cs, 16);
                    cs += __shfl_xor(cs, 32);
                    if (lane < 16) atomicAdd(&colsum[c], cs);
                }
            }
        }
    }
}

// ---------------------------------------------------------------------------
extern "C" void kernel_launch(void* const* d_in, const int* in_sizes, int n_in,
                              void* d_out, int out_size, void* d_ws, size_t ws_size,
                              hipStream_t stream) {
    const float* x   = (const float*)d_in[0];
    const float* Wih = (const float*)d_in[1];
    // d_in[2] = W_hh : unused (h_prev == 0)
    const float* bih = (const float*)d_in[3];
    const float* bhh = (const float*)d_in[4];
    const float* W1  = (const float*)d_in[5];
    const float* b1  = (const float*)d_in[6];
    const float* W2  = (const float*)d_in[7];
    const float* b2  = (const float*)d_in[8];
    const float* Wg  = (const float*)d_in[9];
    const float* bg  = (const float*)d_in[10];
    float* out = (float*)d_out;

    char* w = (char*)d_ws;
    u16* Wihb  = (u16*)w;  w += (size_t)3 * 3072 * 1024 * 2;   // 18.9 MB
    u16* W1b   = (u16*)w;  w += (size_t)3 * 512 * 1024 * 2;    //  3.1 MB
    u16* W2b   = (u16*)w;  w += (size_t)3 * 1024 * 512 * 2;    //  3.1 MB
    u16* curbA = (u16*)w;  w += (size_t)BSZ * ESZ * 2;         // 16.8 MB
    u16* curbB = (u16*)w;  w += (size_t)BSZ * ESZ * 2;         // 16.8 MB
    u16* Amat  = (u16*)w;  w += (size_t)BSZ * 512 * 2;         //  8.4 MB
    u16* sigb  = (u16*)w;  w += (size_t)BSZ * ESZ * 2;         // 16.8 MB
    float* colsum = (float*)w;  w += 4096;                     // 1024 f32
    float* gsum   = (float*)w;  w += 256;                      // 1 f32 (+pad)
    float* sdot   = (float*)w;  w += (size_t)BSZ * 4;          // 32 KB

    // f16 conversions (every call — no persistent state allowed)
    {
        int n4 = N4_WIH + N4_W1 + N4_W2 + N4_X;
        cvt_all_kernel<<<dim3((n4 + 255) / 256), 256, 0, stream>>>(
            Wih, W1, W2, x, Wihb, W1b, W2b, curbA);
    }

    u16* cin = curbA;
    u16* cout = curbB;
    for (int l = 0; l < 3; l++) {
        hipMemsetAsync(colsum, 0, 4096 + 4, stream);  // colsum + gsum
        // act0: Amat = relu(cur@W1^T + b1)  [BM=64, BN=128, grid 512, 48KB LDS]
        gemm_p4_kernel<2, 2, 32, 3, 16, 128, 1024, 0><<<dim3(512), 256, 0, stream>>>(
            cin, W1b + (size_t)l * 512 * 1024, b1 + l * 512, nullptr,
            nullptr, nullptr, nullptr, Amat, nullptr, nullptr, 512);
        // act1: sig = tanh(Amat@W2^T + b2) + colsum  [BM=128, BN=128, grid 512]
        gemm_p4_kernel<4, 2, 16, 4, 8, 128, 512, 1><<<dim3(512), 256, 0, stream>>>(
            Amat, W2b + (size_t)l * 1024 * 512, b2 + l * 1024, nullptr,
            nullptr, nullptr, nullptr, sigb, nullptr, colsum, 1024);
        // gate mean (-> cond) and rank-1 row dots
        gate_kernel<<<dim3(BSZ / 4), 256, 0, stream>>>(
            cin, Wg + l * 1024, bg + l, colsum, gsum, sdot);
        // fused GRU: gi = cur@W_ih^T (+rank-1), cell, += sig  [BM=128, NG=3, grid 1024]
        gemm_p4_kernel<4, 3, 32, 5, 8, 64, 1024, 2><<<dim3(1024), 256, 0, stream>>>(
            cin, Wihb + (size_t)l * 3072 * 1024, bih + l * 3072, bhh + l * 3072,
            sigb, sdot, gsum, (l < 2) ? cout : nullptr,
            (l == 2) ? out : nullptr, nullptr, 1024);
        u16* tmp = cin; cin = cout; cout = tmp;
    }
}